// Round 1
// baseline (2776.477 us; speedup 1.0000x reference)
//
#include <hip/hip_runtime.h>
#include <cstdint>
#include <cstddef>

#define U4    512   // 4*U
#define UNITS 128
#define BATCH 256
#define TSEQ  512
#define FEAT  64

typedef short short8 __attribute__((ext_vector_type(8)));
typedef float f32x4  __attribute__((ext_vector_type(4)));

// ---------------- fast activations (fp32, ~1e-7 rel err) ----------------
__device__ __forceinline__ float sigm(float x) {
    float e = __expf(-x);
    return __fdividef(1.0f, 1.0f + e);
}
__device__ __forceinline__ float tanh_fast(float x) {
    float e = __expf(2.0f * x);
    return 1.0f - __fdividef(2.0f, e + 1.0f);
}

// ---------------- bf16 split helpers (RNE) ----------------
__device__ __forceinline__ unsigned short f2bf(float f) {
    unsigned u = __float_as_uint(f);
    unsigned r = u + 0x7FFFu + ((u >> 16) & 1u);
    return (unsigned short)(r >> 16);
}
__device__ __forceinline__ float bf2f(unsigned short h) {
    return __uint_as_float(((unsigned)h) << 16);
}

// ---------------- projection GEMM (unchanged) ----------------
__global__ __launch_bounds__(256, 4)
void proj_gemm(const float* __restrict__ in, const float* __restrict__ W,
               const float* __restrict__ bias, float* __restrict__ out,
               int K, int sB, int sT, int t0, int tcShift)
{
    const int tid = threadIdx.x;
    const int tx = tid & 31;
    const int ty = tid >> 5;
    const int m0 = blockIdx.x * 64;
    const int n0 = blockIdx.y * 128;
    const int TcMask = (1 << tcShift) - 1;

    __shared__ float As[32][68];
    __shared__ float Bs[32][128];

    float4 acc[8];
    #pragma unroll
    for (int i = 0; i < 8; ++i) acc[i] = make_float4(0.f, 0.f, 0.f, 0.f);

    for (int k0 = 0; k0 < K; k0 += 32) {
        #pragma unroll
        for (int i = 0; i < 8; ++i) {
            int l = i * 256 + tid;
            int row = l >> 5, kk = l & 31;
            int rg = m0 + row;
            int b = rg >> tcShift, tc = rg & TcMask;
            As[kk][row] = in[(size_t)b * sB + (size_t)(t0 + tc) * sT + k0 + kk];
        }
        #pragma unroll
        for (int i = 0; i < 4; ++i) {
            int l = i * 256 + tid;
            int kk = l >> 5, jq = l & 31;
            float4 w4 = *(const float4*)(W + (size_t)(k0 + kk) * U4 + n0 + jq * 4);
            *(float4*)(&Bs[kk][jq * 4]) = w4;
        }
        __syncthreads();
        #pragma unroll
        for (int kk = 0; kk < 32; ++kk) {
            float4 b4 = *(const float4*)(&Bs[kk][tx * 4]);
            float4 a0 = *(const float4*)(&As[kk][ty * 8]);
            float4 a1 = *(const float4*)(&As[kk][ty * 8 + 4]);
            float a[8] = {a0.x, a0.y, a0.z, a0.w, a1.x, a1.y, a1.z, a1.w};
            #pragma unroll
            for (int i = 0; i < 8; ++i) {
                acc[i].x = __builtin_fmaf(a[i], b4.x, acc[i].x);
                acc[i].y = __builtin_fmaf(a[i], b4.y, acc[i].y);
                acc[i].z = __builtin_fmaf(a[i], b4.z, acc[i].z);
                acc[i].w = __builtin_fmaf(a[i], b4.w, acc[i].w);
            }
        }
        __syncthreads();
    }

    float4 bb = *(const float4*)(bias + n0 + tx * 4);
    #pragma unroll
    for (int i = 0; i < 8; ++i) {
        int rg = m0 + ty * 8 + i;
        float4 v = acc[i];
        v.x += bb.x; v.y += bb.y; v.z += bb.z; v.w += bb.w;
        *(float4*)(out + (size_t)rg * U4 + n0 + tx * 4) = v;
    }
}

// ---------------- R -> bf16 hi/lo MFMA B-fragments, GATE-INTERLEAVED ------
// v4 permutation: wave ng owns units [ng*8, ng*8+8), its 32 permuted cols =
//   local = (gate&1)*8 + (u&7) + (gate>>1)*16   (i:0-7, f:8-15, g:16-23, o:24-31)
// so quad0 lane l<8 ends with (i,g) of unit ng*8+l and lane l+8 with (f,o).
// Frag layout per MFMA (16x16x32 bf16 B): lane holds B[k=quad*8+j][n=lane&15].
// Rf[layer][ng(16)][nt(2)][kt(4)][pass(2)][lane(64)][8 shorts].
__global__ __launch_bounds__(256)
void r_frag(const float* __restrict__ R0, const float* __restrict__ R1,
            const float* __restrict__ R2, unsigned short* __restrict__ out)
{
    int gid = blockIdx.x * 256 + threadIdx.x;    // 3 * 16384
    int l    = gid >> 14;
    int r    = gid & 16383;
    int lane = r & 63;
    int fi   = r >> 6;            // 0..255
    int pass = fi & 1;
    int kt   = (fi >> 1) & 3;
    int nt   = (fi >> 3) & 1;
    int ng   = fi >> 4;           // 0..15
    const float* R = (l == 0) ? R0 : (l == 1) ? R1 : R2;

    int n_local = nt * 16 + (lane & 15);         // 0..31
    int gate = n_local >> 3;                     // 0:i 1:f 2:g 3:o
    int u    = ng * 8 + (n_local & 7);
    int col  = gate * UNITS + u;                 // original R column
    int k0   = kt * 32 + (lane >> 4) * 8;
    short8 v;
    #pragma unroll
    for (int j = 0; j < 8; ++j) {
        float x = R[(size_t)(k0 + j) * U4 + col];
        unsigned short hi = f2bf(x);
        unsigned short s = pass ? f2bf(x - bf2f(hi)) : hi;
        v[j] = (short)s;
    }
    *(short8*)(out + (size_t)gid * 8) = v;
}

// ---------------- LSTM recurrence via MFMA (v4: wave-owned units) --------
// 1 block/seq (256 blocks), 1024 threads = 16 waves, 4 waves/SIMD.
// Wave w owns units [w*8, w*8+8): full K=128, 2 ntiles of gate-interleaved
// cols, 2 hi/lo passes -> 16 MFMAs/wave (4 chains of depth 4).
// After MFMA, quad0 lanes hold complete gate pre-acts of the wave's OWN
// units -> phase B is wave-local: one shfl_xor(8) pairs (i,g) with (f,o),
// lanes 0-7 do activations + c/h update + bf16 hi/lo write into a
// double-buffered htab[parity]. ONE __syncthreads per step (was 2 + abuf
// round-trip). Precision path identical to R8 (h and R split bf16 hi/lo,
// fp32 MFMA accum).
__global__ __launch_bounds__(1024)
void lstm_rec(const float* __restrict__ xw, const unsigned short* __restrict__ Rf,
              float* __restrict__ h_state, float* __restrict__ c_state,
              float* __restrict__ h_out, int Tc, int init)
{
    const int tid  = threadIdx.x;
    const int b    = blockIdx.x;
    const int lane = tid & 63;
    const int w    = tid >> 6;       // 0..15, owns units [w*8, w*8+8)
    const int m    = lane & 15;
    const int quad = lane >> 4;

    // double-buffered h table: [parity][hi/lo][128 units (+pad)]
    __shared__ __align__(16) unsigned short htab[2][2][136];

    // B fragments: [nt][kt][pass] = 16 short8 = 64 regs
    short8 bf[2][4][2];
    #pragma unroll
    for (int nt = 0; nt < 2; ++nt)
        #pragma unroll
        for (int kt = 0; kt < 4; ++kt)
            #pragma unroll
            for (int pp = 0; pp < 2; ++pp)
                bf[nt][kt][pp] = *(const short8*)(
                    Rf + ((size_t)(((w * 2 + nt) * 4 + kt) * 2 + pp) * 64 + lane) * 8);

    const int u8 = w * 8 + lane;     // unit for lanes 0..7
    float c = 0.f;
    float hlast = 0.f;
    if (lane < 8 && !init) c = c_state[b * UNITS + u8];
    if (tid < 128) {
        float hv = init ? 0.f : h_state[b * UNITS + tid];
        unsigned short hi = f2bf(hv);
        htab[0][0][tid] = hi;
        htab[0][1][tid] = f2bf(hv - bf2f(hi));
    }
    __syncthreads();

    // xw columns in ORIGINAL gate-major layout for this wave's quad0 lanes:
    // lane l<16: ntile0 col = (l>>3)*128 + w*8 + (l&7) (i or f), ntile1 = +256.
    const float* xwB = xw + (size_t)b * Tc * U4;
    const int xcol0 = ((lane >> 3) & 1) * UNITS + w * 8 + (lane & 7);
    float xa0 = 0.f, xa1 = 0.f;
    if (lane < 16) { xa0 = xwB[xcol0]; xa1 = xwB[xcol0 + 256]; }

    #pragma unroll 1
    for (int t = 0; t < Tc; ++t) {
        const int p = t & 1;

        // ---- A-frags: rows 0=h_hi, 1=h_lo; rows >=2 zero (masked load) ----
        short8 af0 = {0,0,0,0,0,0,0,0};
        short8 af1 = {0,0,0,0,0,0,0,0};
        short8 af2 = {0,0,0,0,0,0,0,0};
        short8 af3 = {0,0,0,0,0,0,0,0};
        if (m < 2) {
            af0 = *(const short8*)(&htab[p][m][ 0 + quad * 8]);
            af1 = *(const short8*)(&htab[p][m][32 + quad * 8]);
            af2 = *(const short8*)(&htab[p][m][64 + quad * 8]);
            af3 = *(const short8*)(&htab[p][m][96 + quad * 8]);
        }

        // prefetch next step's xw under the MFMA chain
        int tn = (t + 1 < Tc) ? (t + 1) : t;
        float y0 = 0.f, y1 = 0.f;
        if (lane < 16) {
            const float* xwN = xwB + (size_t)tn * U4;
            y0 = xwN[xcol0]; y1 = xwN[xcol0 + 256];
        }

        // C init folds xw into pass-a accum (z = Ca.x+Ca.y+Cb.x+Cb.y - xa)
        f32x4 Ca0 = {xa0, xa0, xa0, xa0};
        f32x4 Ca1 = {xa1, xa1, xa1, xa1};
        f32x4 Cb0 = {0.f, 0.f, 0.f, 0.f};
        f32x4 Cb1 = {0.f, 0.f, 0.f, 0.f};

        Ca0 = __builtin_amdgcn_mfma_f32_16x16x32_bf16(af0, bf[0][0][0], Ca0, 0, 0, 0);
        Ca1 = __builtin_amdgcn_mfma_f32_16x16x32_bf16(af0, bf[1][0][0], Ca1, 0, 0, 0);
        Cb0 = __builtin_amdgcn_mfma_f32_16x16x32_bf16(af0, bf[0][0][1], Cb0, 0, 0, 0);
        Cb1 = __builtin_amdgcn_mfma_f32_16x16x32_bf16(af0, bf[1][0][1], Cb1, 0, 0, 0);
        Ca0 = __builtin_amdgcn_mfma_f32_16x16x32_bf16(af1, bf[0][1][0], Ca0, 0, 0, 0);
        Ca1 = __builtin_amdgcn_mfma_f32_16x16x32_bf16(af1, bf[1][1][0], Ca1, 0, 0, 0);
        Cb0 = __builtin_amdgcn_mfma_f32_16x16x32_bf16(af1, bf[0][1][1], Cb0, 0, 0, 0);
        Cb1 = __builtin_amdgcn_mfma_f32_16x16x32_bf16(af1, bf[1][1][1], Cb1, 0, 0, 0);
        Ca0 = __builtin_amdgcn_mfma_f32_16x16x32_bf16(af2, bf[0][2][0], Ca0, 0, 0, 0);
        Ca1 = __builtin_amdgcn_mfma_f32_16x16x32_bf16(af2, bf[1][2][0], Ca1, 0, 0, 0);
        Cb0 = __builtin_amdgcn_mfma_f32_16x16x32_bf16(af2, bf[0][2][1], Cb0, 0, 0, 0);
        Cb1 = __builtin_amdgcn_mfma_f32_16x16x32_bf16(af2, bf[1][2][1], Cb1, 0, 0, 0);
        Ca0 = __builtin_amdgcn_mfma_f32_16x16x32_bf16(af3, bf[0][3][0], Ca0, 0, 0, 0);
        Ca1 = __builtin_amdgcn_mfma_f32_16x16x32_bf16(af3, bf[1][3][0], Ca1, 0, 0, 0);
        Cb0 = __builtin_amdgcn_mfma_f32_16x16x32_bf16(af3, bf[0][3][1], Cb0, 0, 0, 0);
        Cb1 = __builtin_amdgcn_mfma_f32_16x16x32_bf16(af3, bf[1][3][1], Cb1, 0, 0, 0);

        // ---- wave-local phase B ----
        // quad0 lane l<8: z0 = i(u8), z1 = g(u8); lane l+8: z0 = f, z1 = o
        float z0 = Ca0.x + Ca0.y + Cb0.x + Cb0.y - xa0;
        float z1 = Ca1.x + Ca1.y + Cb1.x + Cb1.y - xa1;
        float zf = __shfl_xor(z0, 8);   // lanes<8 receive f-gate preact
        float zo = __shfl_xor(z1, 8);   // lanes<8 receive o-gate preact
        if (lane < 8) {
            float iv = sigm(z0);
            float fv = sigm(zf);
            float gv = tanh_fast(z1);
            float ov = sigm(zo);
            c = __builtin_fmaf(fv, c, iv * gv);
            float hv = ov * tanh_fast(c);
            hlast = hv;
            unsigned short hi = f2bf(hv);
            htab[p ^ 1][0][u8] = hi;
            htab[p ^ 1][1][u8] = f2bf(hv - bf2f(hi));
            if (h_out) h_out[((size_t)b * Tc + t) * UNITS + u8] = hv;
        }
        __syncthreads();   // single barrier: htab[p^1] ready for next step

        xa0 = y0; xa1 = y1;
    }

    if (lane < 8) {
        c_state[b * UNITS + u8] = c;
        h_state[b * UNITS + u8] = hlast;
    }
}

// ---------------- dense head ----------------
__global__ __launch_bounds__(256)
void dense_head(const float* __restrict__ h2, const float* __restrict__ Wd,
                const float* __restrict__ bd, float* __restrict__ out)
{
    int b = threadIdx.x;
    float acc[6];
    #pragma unroll
    for (int o = 0; o < 6; ++o) acc[o] = bd[o];
    #pragma unroll 4
    for (int k = 0; k < UNITS; ++k) {
        float hv = h2[b * UNITS + k];
        #pragma unroll
        for (int o = 0; o < 6; ++o)
            acc[o] = __builtin_fmaf(hv, Wd[k * 6 + o], acc[o]);
    }
    #pragma unroll
    for (int o = 0; o < 6; ++o) out[b * 6 + o] = acc[o];
}

extern "C" void kernel_launch(void* const* d_in, const int* in_sizes, int n_in,
                              void* d_out, int out_size, void* d_ws, size_t ws_size,
                              hipStream_t stream)
{
    (void)in_sizes; (void)n_in; (void)out_size;
    const float* x  = (const float*)d_in[0];
    const float* Ws[3] = {(const float*)d_in[1], (const float*)d_in[4], (const float*)d_in[7]};
    const float* Rs[3] = {(const float*)d_in[2], (const float*)d_in[5], (const float*)d_in[8]};
    const float* bs[3] = {(const float*)d_in[3], (const float*)d_in[6], (const float*)d_in[9]};
    const float* Wd = (const float*)d_in[10];
    const float* bd = (const float*)d_in[11];
    float* out = (float*)d_out;

    int tcShift = 7;
    while (tcShift > 2) {
        size_t need = ((size_t)1 << tcShift) * 655360u + 786432u + 786432u;
        if (need <= ws_size) break;
        --tcShift;
    }
    const int Tc = 1 << tcShift;

    float* xw = (float*)d_ws;                                // [B][Tc][512]
    float* hc = xw + (size_t)BATCH * Tc * U4;                // [B][Tc][128]
    float* hs = hc + (size_t)BATCH * Tc * UNITS;             // 3 x [B][128]
    float* cs = hs + 3 * BATCH * UNITS;                      // 3 x [B][128]
    unsigned short* Rf = (unsigned short*)(cs + 3 * BATCH * UNITS); // 3 x 128K shorts

    // precompute gate-interleaved bf16 hi/lo MFMA B-fragments of R0..R2
    r_frag<<<192, 256, 0, stream>>>(Rs[0], Rs[1], Rs[2], Rf);

    const int nChunks = TSEQ / Tc;
    for (int ch = 0; ch < nChunks; ++ch) {
        const int t0 = ch * Tc;
        for (int layer = 0; layer < 3; ++layer) {
            const float* in = (layer == 0) ? x : hc;
            const int K  = (layer == 0) ? FEAT : UNITS;
            const int sB = (layer == 0) ? TSEQ * FEAT : Tc * UNITS;
            const int sT = K;
            const int pt0 = (layer == 0) ? t0 : 0;

            dim3 grid(BATCH * Tc / 64, 4);
            proj_gemm<<<grid, 256, 0, stream>>>(in, Ws[layer], bs[layer], xw,
                                                K, sB, sT, pt0, tcShift);

            float* hOut = (layer < 2) ? hc : nullptr;
            lstm_rec<<<BATCH, 1024, 0, stream>>>(xw, Rf + (size_t)layer * 131072,
                                                 hs + layer * BATCH * UNITS,
                                                 cs + layer * BATCH * UNITS,
                                                 hOut, Tc, (ch == 0) ? 1 : 0);
        }
    }
    dense_head<<<1, 256, 0, stream>>>(hs + 2 * BATCH * UNITS, Wd, bd, out);
}

// Round 2
// 2401.354 us; speedup vs baseline: 1.1562x; 1.1562x over previous
//
#include <hip/hip_runtime.h>
#include <cstdint>
#include <cstddef>

#define U4    512   // 4*U
#define UNITS 128
#define BATCH 256
#define TSEQ  512
#define FEAT  64

typedef short short8 __attribute__((ext_vector_type(8)));
typedef float f32x4  __attribute__((ext_vector_type(4)));

// ---------------- fast activations (fp32, ~1e-7 rel err) ----------------
__device__ __forceinline__ float sigm(float x) {
    float e = __expf(-x);
    return __fdividef(1.0f, 1.0f + e);
}
__device__ __forceinline__ float tanh_fast(float x) {
    float e = __expf(2.0f * x);
    return 1.0f - __fdividef(2.0f, e + 1.0f);
}

// ---------------- bf16 split helpers (RNE) ----------------
__device__ __forceinline__ unsigned short f2bf(float f) {
    unsigned u = __float_as_uint(f);
    unsigned r = u + 0x7FFFu + ((u >> 16) & 1u);
    return (unsigned short)(r >> 16);
}
__device__ __forceinline__ float bf2f(unsigned short h) {
    return __uint_as_float(((unsigned)h) << 16);
}

// ---------------- projection GEMM (unchanged) ----------------
__global__ __launch_bounds__(256, 4)
void proj_gemm(const float* __restrict__ in, const float* __restrict__ W,
               const float* __restrict__ bias, float* __restrict__ out,
               int K, int sB, int sT, int t0, int tcShift)
{
    const int tid = threadIdx.x;
    const int tx = tid & 31;
    const int ty = tid >> 5;
    const int m0 = blockIdx.x * 64;
    const int n0 = blockIdx.y * 128;
    const int TcMask = (1 << tcShift) - 1;

    __shared__ float As[32][68];
    __shared__ float Bs[32][128];

    float4 acc[8];
    #pragma unroll
    for (int i = 0; i < 8; ++i) acc[i] = make_float4(0.f, 0.f, 0.f, 0.f);

    for (int k0 = 0; k0 < K; k0 += 32) {
        #pragma unroll
        for (int i = 0; i < 8; ++i) {
            int l = i * 256 + tid;
            int row = l >> 5, kk = l & 31;
            int rg = m0 + row;
            int b = rg >> tcShift, tc = rg & TcMask;
            As[kk][row] = in[(size_t)b * sB + (size_t)(t0 + tc) * sT + k0 + kk];
        }
        #pragma unroll
        for (int i = 0; i < 4; ++i) {
            int l = i * 256 + tid;
            int kk = l >> 5, jq = l & 31;
            float4 w4 = *(const float4*)(W + (size_t)(k0 + kk) * U4 + n0 + jq * 4);
            *(float4*)(&Bs[kk][jq * 4]) = w4;
        }
        __syncthreads();
        #pragma unroll
        for (int kk = 0; kk < 32; ++kk) {
            float4 b4 = *(const float4*)(&Bs[kk][tx * 4]);
            float4 a0 = *(const float4*)(&As[kk][ty * 8]);
            float4 a1 = *(const float4*)(&As[kk][ty * 8 + 4]);
            float a[8] = {a0.x, a0.y, a0.z, a0.w, a1.x, a1.y, a1.z, a1.w};
            #pragma unroll
            for (int i = 0; i < 8; ++i) {
                acc[i].x = __builtin_fmaf(a[i], b4.x, acc[i].x);
                acc[i].y = __builtin_fmaf(a[i], b4.y, acc[i].y);
                acc[i].z = __builtin_fmaf(a[i], b4.z, acc[i].z);
                acc[i].w = __builtin_fmaf(a[i], b4.w, acc[i].w);
            }
        }
        __syncthreads();
    }

    float4 bb = *(const float4*)(bias + n0 + tx * 4);
    #pragma unroll
    for (int i = 0; i < 8; ++i) {
        int rg = m0 + ty * 8 + i;
        float4 v = acc[i];
        v.x += bb.x; v.y += bb.y; v.z += bb.z; v.w += bb.w;
        *(float4*)(out + (size_t)rg * U4 + n0 + tx * 4) = v;
    }
}

// ---------------- R -> bf16 hi/lo MFMA B-fragments, v5 permutation -------
// 8 waves/block. Wave w owns units [w*16, w*16+16). Tile j (j=0..3) = gate j
// of those 16 units, lane m <-> unit w*16+m. After MFMA, quad0 lane m holds
// all four gate pre-acts of its OWN unit in-lane (no shuffles).
// Frag layout per MFMA (16x16x32 bf16 B): lane holds B[k=kt*32+quad*8+j][n=lane&15].
// Rf[layer][w(8)][gate(4)][kt(4)][pass(2)][lane(64)][8 shorts].
__global__ __launch_bounds__(256)
void r_frag(const float* __restrict__ R0, const float* __restrict__ R1,
            const float* __restrict__ R2, unsigned short* __restrict__ out)
{
    int gid = blockIdx.x * 256 + threadIdx.x;    // 3 * 16384
    int l    = gid >> 14;
    int r    = gid & 16383;
    int lane = r & 63;
    int fi   = r >> 6;            // 0..255
    int pass = fi & 1;
    int kt   = (fi >> 1) & 3;
    int gate = (fi >> 3) & 3;
    int w    = fi >> 5;           // 0..7
    const float* R = (l == 0) ? R0 : (l == 1) ? R1 : R2;

    int col = gate * UNITS + w * 16 + (lane & 15);   // original R column
    int k0  = kt * 32 + (lane >> 4) * 8;
    short8 v;
    #pragma unroll
    for (int j = 0; j < 8; ++j) {
        float x = R[(size_t)(k0 + j) * U4 + col];
        unsigned short hi = f2bf(x);
        unsigned short s = pass ? f2bf(x - bf2f(hi)) : hi;
        v[j] = (short)s;
    }
    *(short8*)(out + (size_t)gid * 8) = v;
}

// ---------------- LSTM recurrence via MFMA (v5: 8 waves, gate-per-tile) --
// 1 block/seq (256 blocks), 512 threads = 8 waves, 2 waves/SIMD.
// Wave w: full K=128, 4 gate-tiles of its 16 units, 2 hi/lo passes
// -> 32 MFMAs/wave (4 chains of depth 8). B-frags 32 short8 = 128 VGPRs
// (fits the 256-reg cap at 2 waves/SIMD, __launch_bounds__(512,2)).
// After MFMA, quad0 lane m holds i,f,g,o pre-acts of unit w*16+m IN-LANE:
// phase B = activations on 16 lanes/wave, no shuffle, no abuf, ONE barrier
// per step (double-buffered htab). xw folded into C.x init (z = C.x + C.y).
// v4 lesson: exec-masked instrs still cost full issue per wave -> the
// scalar tail is replicated over 8 waves here (v3: 2 serial waves + 2
// barriers; v4: 16 waves). Precision path identical to R8/v4 (validated).
__global__ __launch_bounds__(512, 2)
void lstm_rec(const float* __restrict__ xw, const unsigned short* __restrict__ Rf,
              float* __restrict__ h_state, float* __restrict__ c_state,
              float* __restrict__ h_out, int Tc, int init)
{
    const int tid  = threadIdx.x;
    const int b    = blockIdx.x;
    const int lane = tid & 63;
    const int w    = tid >> 6;       // 0..7, owns units [w*16, w*16+16)
    const int m    = lane & 15;
    const int quad = lane >> 4;

    // double-buffered h table: [parity][hi/lo][128 units (+pad)]
    __shared__ __align__(16) unsigned short htab[2][2][136];

    // B fragments: [gate][kt][pass] = 32 short8 = 128 VGPRs
    short8 bf[4][4][2];
    #pragma unroll
    for (int g = 0; g < 4; ++g)
        #pragma unroll
        for (int kt = 0; kt < 4; ++kt)
            #pragma unroll
            for (int pp = 0; pp < 2; ++pp)
                bf[g][kt][pp] = *(const short8*)(
                    Rf + ((size_t)((((w * 4 + g) * 4 + kt) * 2) + pp) * 64 + lane) * 8);

    const int u16 = w * 16 + m;      // unit for quad0 lanes
    float c = 0.f;
    float hlast = 0.f;
    if (lane < 16 && !init) c = c_state[b * UNITS + u16];
    if (tid < 128) {
        float hv = init ? 0.f : h_state[b * UNITS + tid];
        unsigned short hi = f2bf(hv);
        htab[0][0][tid] = hi;
        htab[0][1][tid] = f2bf(hv - bf2f(hi));
    }
    __syncthreads();

    // xw columns for quad0 lane m: gate g -> xw[t][g*128 + w*16 + m]
    const float* xwB = xw + (size_t)b * Tc * U4;
    const int xcol = w * 16 + m;
    float xa0 = 0.f, xa1 = 0.f, xa2 = 0.f, xa3 = 0.f;
    if (lane < 16) {
        xa0 = xwB[xcol];
        xa1 = xwB[xcol + 128];
        xa2 = xwB[xcol + 256];
        xa3 = xwB[xcol + 384];
    }

    // A-frags: rows 0=h_hi, 1=h_lo; rows >=2 stay zero across all steps
    // (masked ds_read only overwrites lanes m<2; others keep the 0 init).
    short8 af[4];
    #pragma unroll
    for (int kt = 0; kt < 4; ++kt) af[kt] = short8{0,0,0,0,0,0,0,0};

    #pragma unroll 1
    for (int t = 0; t < Tc; ++t) {
        const int p = t & 1;

        if (m < 2) {
            #pragma unroll
            for (int kt = 0; kt < 4; ++kt)
                af[kt] = *(const short8*)(&htab[p][m][kt * 32 + quad * 8]);
        }

        // prefetch next step's xw under the MFMA chain
        int tn = (t + 1 < Tc) ? (t + 1) : t;
        float y0 = 0.f, y1 = 0.f, y2 = 0.f, y3 = 0.f;
        if (lane < 16) {
            const float* xwN = xwB + (size_t)tn * U4;
            y0 = xwN[xcol];
            y1 = xwN[xcol + 128];
            y2 = xwN[xcol + 256];
            y3 = xwN[xcol + 384];
        }

        // C init: xw folded into row-0 slot -> z = C.x + C.y (no subtract)
        f32x4 C0 = {xa0, 0.f, 0.f, 0.f};
        f32x4 C1 = {xa1, 0.f, 0.f, 0.f};
        f32x4 C2 = {xa2, 0.f, 0.f, 0.f};
        f32x4 C3 = {xa3, 0.f, 0.f, 0.f};

        #pragma unroll
        for (int kt = 0; kt < 4; ++kt) {
            #pragma unroll
            for (int pp = 0; pp < 2; ++pp) {
                C0 = __builtin_amdgcn_mfma_f32_16x16x32_bf16(af[kt], bf[0][kt][pp], C0, 0, 0, 0);
                C1 = __builtin_amdgcn_mfma_f32_16x16x32_bf16(af[kt], bf[1][kt][pp], C1, 0, 0, 0);
                C2 = __builtin_amdgcn_mfma_f32_16x16x32_bf16(af[kt], bf[2][kt][pp], C2, 0, 0, 0);
                C3 = __builtin_amdgcn_mfma_f32_16x16x32_bf16(af[kt], bf[3][kt][pp], C3, 0, 0, 0);
            }
        }

        // ---- wave-local phase B: quad0 lane m owns unit w*16+m ----
        if (lane < 16) {
            float zi = C0.x + C0.y;
            float zf = C1.x + C1.y;
            float zg = C2.x + C2.y;
            float zo = C3.x + C3.y;
            float iv = sigm(zi);
            float fv = sigm(zf);
            float gv = tanh_fast(zg);
            float ov = sigm(zo);
            c = __builtin_fmaf(fv, c, iv * gv);
            float hv = ov * tanh_fast(c);
            hlast = hv;
            unsigned short hi = f2bf(hv);
            htab[p ^ 1][0][u16] = hi;
            htab[p ^ 1][1][u16] = f2bf(hv - bf2f(hi));
            if (h_out) h_out[((size_t)b * Tc + t) * UNITS + u16] = hv;
        }
        __syncthreads();   // single barrier: htab[p^1] ready for next step

        xa0 = y0; xa1 = y1; xa2 = y2; xa3 = y3;
    }

    if (lane < 16) {
        c_state[b * UNITS + u16] = c;
        h_state[b * UNITS + u16] = hlast;
    }
}

// ---------------- dense head ----------------
__global__ __launch_bounds__(256)
void dense_head(const float* __restrict__ h2, const float* __restrict__ Wd,
                const float* __restrict__ bd, float* __restrict__ out)
{
    int b = threadIdx.x;
    float acc[6];
    #pragma unroll
    for (int o = 0; o < 6; ++o) acc[o] = bd[o];
    #pragma unroll 4
    for (int k = 0; k < UNITS; ++k) {
        float hv = h2[b * UNITS + k];
        #pragma unroll
        for (int o = 0; o < 6; ++o)
            acc[o] = __builtin_fmaf(hv, Wd[k * 6 + o], acc[o]);
    }
    #pragma unroll
    for (int o = 0; o < 6; ++o) out[b * 6 + o] = acc[o];
}

extern "C" void kernel_launch(void* const* d_in, const int* in_sizes, int n_in,
                              void* d_out, int out_size, void* d_ws, size_t ws_size,
                              hipStream_t stream)
{
    (void)in_sizes; (void)n_in; (void)out_size;
    const float* x  = (const float*)d_in[0];
    const float* Ws[3] = {(const float*)d_in[1], (const float*)d_in[4], (const float*)d_in[7]};
    const float* Rs[3] = {(const float*)d_in[2], (const float*)d_in[5], (const float*)d_in[8]};
    const float* bs[3] = {(const float*)d_in[3], (const float*)d_in[6], (const float*)d_in[9]};
    const float* Wd = (const float*)d_in[10];
    const float* bd = (const float*)d_in[11];
    float* out = (float*)d_out;

    int tcShift = 7;
    while (tcShift > 2) {
        size_t need = ((size_t)1 << tcShift) * 655360u + 786432u + 786432u;
        if (need <= ws_size) break;
        --tcShift;
    }
    const int Tc = 1 << tcShift;

    float* xw = (float*)d_ws;                                // [B][Tc][512]
    float* hc = xw + (size_t)BATCH * Tc * U4;                // [B][Tc][128]
    float* hs = hc + (size_t)BATCH * Tc * UNITS;             // 3 x [B][128]
    float* cs = hs + 3 * BATCH * UNITS;                      // 3 x [B][128]
    unsigned short* Rf = (unsigned short*)(cs + 3 * BATCH * UNITS); // 3 x 128K shorts

    // precompute v5-permuted bf16 hi/lo MFMA B-fragments of R0..R2
    r_frag<<<192, 256, 0, stream>>>(Rs[0], Rs[1], Rs[2], Rf);

    const int nChunks = TSEQ / Tc;
    for (int ch = 0; ch < nChunks; ++ch) {
        const int t0 = ch * Tc;
        for (int layer = 0; layer < 3; ++layer) {
            const float* in = (layer == 0) ? x : hc;
            const int K  = (layer == 0) ? FEAT : UNITS;
            const int sB = (layer == 0) ? TSEQ * FEAT : Tc * UNITS;
            const int sT = K;
            const int pt0 = (layer == 0) ? t0 : 0;

            dim3 grid(BATCH * Tc / 64, 4);
            proj_gemm<<<grid, 256, 0, stream>>>(in, Ws[layer], bs[layer], xw,
                                                K, sB, sT, pt0, tcShift);

            float* hOut = (layer < 2) ? hc : nullptr;
            lstm_rec<<<BATCH, 512, 0, stream>>>(xw, Rf + (size_t)layer * 131072,
                                                hs + layer * BATCH * UNITS,
                                                cs + layer * BATCH * UNITS,
                                                hOut, Tc, (ch == 0) ? 1 : 0);
        }
    }
    dense_head<<<1, 256, 0, stream>>>(hs + 2 * BATCH * UNITS, Wd, bd, out);
}